// Round 2
// baseline (775.751 us; speedup 1.0000x reference)
//
#include <hip/hip_runtime.h>
#include <hip/hip_bf16.h>
#include <cstdint>

typedef unsigned short u16;
typedef unsigned int u32;
typedef float f32x4 __attribute__((ext_vector_type(4)));
typedef short bf16x8 __attribute__((ext_vector_type(8)));

#define T_TOK 8192
#define HID 2048
#define NH 16
#define NKV 4
#define HD 128
#define QKVN 3072   // (16+2*4)*128
#define CHUNK 64
#define NC 128      // 8192/64

__device__ __forceinline__ float bf2f(u16 h){
  u32 u = ((u32)h) << 16;
  return __builtin_bit_cast(float, u);
}
__device__ __forceinline__ u16 f2bf(float f){
  u32 u = __builtin_bit_cast(u32, f);
  u32 r = (u + 0x7fffu + ((u >> 16) & 1u)) >> 16;
  return (u16)r;
}
__device__ __forceinline__ u32 pack2(float a, float b){
  return (u32)f2bf(a) | ((u32)f2bf(b) << 16);
}

// ---------------------------------------------------------------------------
// GEMM: Y[M,N] = X[M,K] @ W[K,N] (W given as bf16 Wt[N,K]) (+bias,+act)
// XT: float (converted to bf16 during staging) or u16 (bf16 already).
// YT: u16 (bf16 store) or float.
// mode 0: plain. mode 1: qkv epilogue (bias f32; relu n<2560; *D^-0.5 n<2048)
// 128x128 tile, BK=32, 4 waves, each 2x2 quadrant of 4x4 16x16x32 MFMAs.
// ---------------------------------------------------------------------------
template<typename XT, typename YT>
__global__ __launch_bounds__(256) void gemm_tpl(
    const XT* __restrict__ X, const u16* __restrict__ Wt,
    const float* __restrict__ bias, YT* __restrict__ Y,
    int M, int N, int K, int mode)
{
  __shared__ u16 As[128*40];
  __shared__ u16 Bs[128*40];
  const int tid = threadIdx.x;
  const int lane = tid & 63;
  const int wave = tid >> 6;
  const int wm = wave >> 1, wn = wave & 1;
  const int bm0 = blockIdx.x * 128, bn0 = blockIdx.y * 128;

  f32x4 acc[4][4];
  #pragma unroll
  for (int i=0;i<4;i++)
    #pragma unroll
    for (int j=0;j<4;j++) acc[i][j] = f32x4{0.f,0.f,0.f,0.f};

  const int r = tid >> 2, c8 = (tid & 3) << 3;
  const int mrow = lane & 15, q8 = (lane >> 4) << 3;

  for (int k0 = 0; k0 < K; k0 += 32) {
    #pragma unroll
    for (int p=0;p<2;p++){
      int rr = r + p*64;
      if (sizeof(XT) == 4) {   // f32 input: load 8 floats, pack to bf16
        const float* xp = (const float*)X + (size_t)(bm0+rr)*K + k0 + c8;
        float4 a0 = *(const float4*)xp;
        float4 a1 = *(const float4*)(xp + 4);
        uint4 pk;
        pk.x = pack2(a0.x, a0.y); pk.y = pack2(a0.z, a0.w);
        pk.z = pack2(a1.x, a1.y); pk.w = pack2(a1.z, a1.w);
        *(uint4*)(As + rr*40 + c8) = pk;
      } else {                 // bf16 input
        uint4 da = *(const uint4*)((const u16*)X + (size_t)(bm0+rr)*K + k0 + c8);
        *(uint4*)(As + rr*40 + c8) = da;
      }
      uint4 db = *(const uint4*)(Wt + (size_t)(bn0+rr)*K + k0 + c8);
      *(uint4*)(Bs + rr*40 + c8) = db;
    }
    __syncthreads();
    bf16x8 af[4], bfr[4];
    #pragma unroll
    for (int i=0;i<4;i++){
      af[i]  = *(const bf16x8*)(As + (wm*64 + i*16 + mrow)*40 + q8);
      bfr[i] = *(const bf16x8*)(Bs + (wn*64 + i*16 + mrow)*40 + q8);
    }
    #pragma unroll
    for (int i=0;i<4;i++)
      #pragma unroll
      for (int j=0;j<4;j++)
        acc[i][j] = __builtin_amdgcn_mfma_f32_16x16x32_bf16(af[i], bfr[j], acc[i][j], 0, 0, 0);
    __syncthreads();
  }
  // epilogue: C/D layout col=lane&15, row=(lane>>4)*4+reg (m89-verified)
  #pragma unroll
  for (int i=0;i<4;i++){
    int row = bm0 + wm*64 + i*16 + (lane>>4)*4;
    #pragma unroll
    for (int j=0;j<4;j++){
      int col = bn0 + wn*64 + j*16 + (lane&15);
      float bv = 0.f;
      if (mode == 1) bv = bias[col];
      #pragma unroll
      for (int rr2=0;rr2<4;rr2++){
        float v = acc[i][j][rr2] + bv;
        if (mode == 1 && col < 2560){
          v = fmaxf(v, 0.f);
          if (col < 2048) v *= 0.08838834764831845f;  // D^-0.5
        }
        if (sizeof(YT) == 2) Y[(size_t)(row+rr2)*N + col] = (YT)f2bf(v);
        else                 Y[(size_t)(row+rr2)*N + col] = (YT)v;
      }
    }
  }
}

// in[R,C] (f32) -> out[C,R] (bf16), 32x32 LDS tiles
__global__ __launch_bounds__(256) void transpose_f2b(
    const float* __restrict__ in, u16* __restrict__ out, int R, int C)
{
  __shared__ float tile[32][33];
  int c0 = blockIdx.x*32, r0 = blockIdx.y*32;
  int tx = threadIdx.x & 31, ty = threadIdx.x >> 5;
  #pragma unroll
  for (int p=0;p<4;p++) tile[ty + p*8][tx] = in[(size_t)(r0 + ty + p*8)*C + c0 + tx];
  __syncthreads();
  #pragma unroll
  for (int p=0;p<4;p++) out[(size_t)(c0 + ty + p*8)*R + r0 + tx] = f2bf(tile[tx][ty + p*8]);
}

// gate low-rank stage 1: tmp[T,16] = hs[T,2048] @ w0[2048,16]; one wave per row
__global__ __launch_bounds__(256) void gk1_kernel(
    const float* __restrict__ hs, const float* __restrict__ w0, float* __restrict__ tmp)
{
  int row = blockIdx.x*4 + (threadIdx.x >> 6);
  int lane = threadIdx.x & 63;
  float acc[16];
  #pragma unroll
  for (int n=0;n<16;n++) acc[n]=0.f;
  for (int k = lane; k < HID; k += 64){
    float h = hs[(size_t)row*HID + k];
    const float* wr = w0 + (size_t)k*16;
    #pragma unroll
    for (int q=0;q<4;q++){
      float4 wv = *(const float4*)(wr + q*4);
      acc[q*4+0] += h*wv.x; acc[q*4+1] += h*wv.y;
      acc[q*4+2] += h*wv.z; acc[q*4+3] += h*wv.w;
    }
  }
  #pragma unroll
  for (int n=0;n<16;n++){
    #pragma unroll
    for (int off=32; off>0; off>>=1)
      acc[n] += __shfl_down(acc[n], off);
  }
  if (lane == 0){
    #pragma unroll
    for (int n=0;n<16;n++) tmp[(size_t)row*16 + n] = acc[n];
  }
}

// gate stage 2: g[T,512] = logsigmoid(tmp @ w1 + b1) / 16
__global__ __launch_bounds__(256) void gk2_kernel(
    const float* __restrict__ tmp, const float* __restrict__ w1,
    const float* __restrict__ b1, float* __restrict__ g)
{
  int id = blockIdx.x*256 + threadIdx.x;
  int rrow = id >> 9, n = id & 511;
  float a = b1[n];
  #pragma unroll
  for (int k=0;k<16;k++)
    a += tmp[(size_t)rrow*16 + k] * w1[k*512 + n];
  // log_sigmoid(x) = min(x,0) - log1p(exp(-|x|))
  float ls = fminf(a, 0.f) - log1pf(__expf(-fabsf(a)));
  g[id] = ls * 0.0625f;
}

// Per (chunk c, kv-head h): cumsum gates b_t[i] (store decay), expB=e^{b_63},
// Kmat[i][j] = sum_t e^{B[i]-b_t[i]} k_t[i] v_t[j]
__global__ __launch_bounds__(256) void chunk_stats_kernel(
    const u16* __restrict__ qkv, const float* __restrict__ g,
    float* __restrict__ decay, float* __restrict__ expB, float* __restrict__ Kmat)
{
  __shared__ float bL[CHUNK*HD];   // gates -> cumsum -> kd (in place)
  __shared__ float vL[CHUNK*HD];
  const int c = blockIdx.x, h = blockIdx.y;
  const int tid = threadIdx.x;
  for (int off = tid; off < CHUNK*HD; off += 256){
    int t = off >> 7, i = off & 127;
    bL[off] = g[(size_t)(c*CHUNK + t)*512 + h*HD + i];
  }
  __syncthreads();
  if (tid < HD){
    float run = 0.f;
    for (int t=0;t<CHUNK;t++){ run += bL[t*HD + tid]; bL[t*HD + tid] = run; }
    expB[((size_t)c*NKV + h)*HD + tid] = __expf(run);
  }
  __syncthreads();
  const int myi = tid & 127;
  float Bfin = bL[63*HD + myi];
  __syncthreads();   // all Bfin reads before in-place kd overwrite
  for (int off = tid; off < CHUNK*HD; off += 256){
    int t = off >> 7, i = off & 127;   // i == myi for all iterations
    float b = bL[off];
    decay[(((size_t)c*NKV + h)*CHUNK + t)*HD + i] = b;
    float kv = bf2f(qkv[(size_t)(c*CHUNK + t)*QKVN + 2048 + h*HD + i]);
    bL[off] = __expf(Bfin - b) * kv;
    vL[off] = bf2f(qkv[(size_t)(c*CHUNK + t)*QKVN + 2560 + h*HD + i]);
  }
  __syncthreads();
  const int ii = tid >> 1, jh = (tid & 1) * 64;
  float acc[64];
  #pragma unroll
  for (int z=0;z<64;z++) acc[z]=0.f;
  for (int t=0;t<CHUNK;t++){
    float kd = bL[t*HD + ii];
    const float4* vp = (const float4*)(vL + t*HD + jh);
    #pragma unroll
    for (int jj=0;jj<16;jj++){
      float4 vv = vp[jj];
      acc[jj*4+0] += kd*vv.x; acc[jj*4+1] += kd*vv.y;
      acc[jj*4+2] += kd*vv.z; acc[jj*4+3] += kd*vv.w;
    }
  }
  float* Kp = Kmat + (((size_t)c*NKV + h)*HD + ii)*HD + jh;
  #pragma unroll
  for (int jj=0;jj<16;jj++)
    *(float4*)(Kp + jj*4) = make_float4(acc[jj*4+0],acc[jj*4+1],acc[jj*4+2],acc[jj*4+3]);
}

// Sequential over 128 chunks; each thread owns one (h,i,j) scalar recurrence.
// Sbuf[c] = state at START of chunk c.
__global__ __launch_bounds__(256) void state_scan_kernel(
    const float* __restrict__ Kmat, const float* __restrict__ expB, float* __restrict__ Sbuf)
{
  int wid = blockIdx.x;                 // 256 blocks
  int h = wid >> 6, i2 = wid & 63;
  int i = i2*2 + (threadIdx.x >> 7);
  int j = threadIdx.x & 127;
  size_t base = ((size_t)h*HD + i)*HD + j;
  float S = 0.f;
  for (int c=0;c<NC;c++){
    size_t off = (size_t)c*(NKV*HD*HD) + base;
    Sbuf[off] = S;
    S = expB[((size_t)c*NKV + h)*HD + i] * S + Kmat[off];
  }
}

// Per (chunk, q-head): A[t][s] = (t>=s) ? sum_i qe[t][i]*kd[s][i] : 0
__global__ __launch_bounds__(256) void attn_a_kernel(
    const u16* __restrict__ qkv, const float* __restrict__ decay, float* __restrict__ Abuf)
{
  __shared__ float qeT[HD*65];   // [i][t]
  __shared__ u16   kdT[HD*66];   // [i][t] bf16
  const int c = blockIdx.x, qh = blockIdx.y, h = qh >> 2;
  const int tid = threadIdx.x;
  for (int off = tid; off < CHUNK*HD; off += 256){
    int t = off >> 7, i = off & 127;
    size_t tok = (size_t)c*CHUNK + t;
    float b = decay[(((size_t)c*NKV + h)*CHUNK + t)*HD + i];
    float q = bf2f(qkv[tok*QKVN + qh*HD + i]);          // relu+scale done in GEMM
    float k = bf2f(qkv[tok*QKVN + 2048 + h*HD + i]);    // relu done in GEMM
    qeT[i*65 + t] = q * __expf(b);
    kdT[i*66 + t] = f2bf(k * __expf(-b));
  }
  __syncthreads();
  const int tb = (tid >> 4)*4, sb = (tid & 15)*4;
  float a[4][4];
  #pragma unroll
  for (int x=0;x<4;x++)
    #pragma unroll
    for (int y=0;y<4;y++) a[x][y]=0.f;
  for (int i=0;i<HD;i++){
    float qv[4], kv[4];
    #pragma unroll
    for (int e=0;e<4;e++){ qv[e] = qeT[i*65 + tb + e]; kv[e] = bf2f(kdT[i*66 + sb + e]); }
    #pragma unroll
    for (int x=0;x<4;x++)
      #pragma unroll
      for (int y=0;y<4;y++) a[x][y] += qv[x]*kv[y];
  }
  float* Ab = Abuf + ((size_t)c*NH + qh)*4096;
  #pragma unroll
  for (int x=0;x<4;x++)
    #pragma unroll
    for (int y=0;y<4;y++){
      int t = tb + x, s = sb + y;
      Ab[t*64 + s] = (t >= s) ? a[x][y] : 0.f;
    }
}

// Per (chunk, q-head): o = qe @ S_start + A @ V, then per-row RMSNorm -> obuf (bf16)
__global__ __launch_bounds__(256) void attn_o_kernel(
    const u16* __restrict__ qkv, const float* __restrict__ decay,
    const float* __restrict__ Sbuf, const float* __restrict__ Abuf,
    const float* __restrict__ gw, u16* __restrict__ obuf)
{
  __shared__ float smem[128*65 + 32*128];  // qeT + S-stage; reused as oL + rstd
  float* qeT = smem;
  float* sSt = smem + 128*65;
  const int c = blockIdx.x, qh = blockIdx.y, h = qh >> 2;
  const int tid = threadIdx.x;
  for (int off = tid; off < CHUNK*HD; off += 256){
    int t = off >> 7, i = off & 127;
    size_t tok = (size_t)c*CHUNK + t;
    float b = decay[(((size_t)c*NKV + h)*CHUNK + t)*HD + i];
    float q = bf2f(qkv[tok*QKVN + qh*HD + i]);
    qeT[i*65 + t] = q * __expf(b);
  }
  __syncthreads();
  const int tb = (tid >> 4)*4, jb = (tid & 15)*8;
  float o[4][8];
  #pragma unroll
  for (int x=0;x<4;x++)
    #pragma unroll
    for (int y=0;y<8;y++) o[x][y]=0.f;
  const float* Srow = Sbuf + ((size_t)c*NKV + h)*(HD*HD);
  for (int ic=0; ic<HD; ic+=32){
    #pragma unroll
    for (int p=0;p<4;p++){
      int fi = tid + p*256;
      ((float4*)sSt)[fi] = ((const float4*)(Srow + (size_t)ic*HD))[fi];
    }
    __syncthreads();
    for (int iiq=0; iiq<32; iiq++){
      int i = ic + iiq;
      float qv[4];
      #pragma unroll
      for (int e=0;e<4;e++) qv[e] = qeT[i*65 + tb + e];
      float4 s0 = *(const float4*)(sSt + iiq*HD + jb);
      float4 s1 = *(const float4*)(sSt + iiq*HD + jb + 4);
      float sv[8] = {s0.x,s0.y,s0.z,s0.w,s1.x,s1.y,s1.z,s1.w};
      #pragma unroll
      for (int x=0;x<4;x++)
        #pragma unroll
        for (int y=0;y<8;y++) o[x][y] += qv[x]*sv[y];
    }
    __syncthreads();
  }
  const float* Ab = Abuf + ((size_t)c*NH + qh)*4096;
  for (int s=0; s<CHUNK; s++){
    float av[4];
    #pragma unroll
    for (int e=0;e<4;e++) av[e] = Ab[(tb+e)*64 + s];
    uint4 vv = *(const uint4*)(qkv + (size_t)(c*CHUNK + s)*QKVN + 2560 + h*HD + jb);
    u32 vp[4] = {vv.x, vv.y, vv.z, vv.w};
    float vf[8];
    #pragma unroll
    for (int e=0;e<4;e++){ vf[2*e] = bf2f((u16)(vp[e]&0xffffu)); vf[2*e+1] = bf2f((u16)(vp[e]>>16)); }
    #pragma unroll
    for (int x=0;x<4;x++)
      #pragma unroll
      for (int y=0;y<8;y++) o[x][y] += av[x]*vf[y];
  }
  __syncthreads();
  float* oL = smem;               // [64][129]
  float* rst = smem + 64*129;
  #pragma unroll
  for (int x=0;x<4;x++)
    #pragma unroll
    for (int y=0;y<8;y++) oL[(tb+x)*129 + jb + y] = o[x][y];
  __syncthreads();
  if (tid < 64){
    float ss = 0.f;
    for (int j=0;j<HD;j++){ float x = oL[tid*129 + j]; ss += x*x; }
    rst[tid] = rsqrtf(ss * (1.f/128.f) + 1e-6f);
  }
  __syncthreads();
  for (int off = tid; off < CHUNK*HD; off += 256){
    int t = off >> 7, i = off & 127;
    float val = oL[t*129 + i] * rst[t] * gw[i];
    obuf[(size_t)(c*CHUNK + t)*(NH*HD) + qh*HD + i] = f2bf(val);
  }
}

extern "C" void kernel_launch(void* const* d_in, const int* in_sizes, int n_in,
                              void* d_out, int out_size, void* d_ws, size_t ws_size,
                              hipStream_t stream)
{
  const float* hs   = (const float*)d_in[0];
  const float* Wqkv = (const float*)d_in[1];
  const float* bqkv = (const float*)d_in[2];
  const float* w0   = (const float*)d_in[3];
  const float* w1   = (const float*)d_in[4];
  const float* b1   = (const float*)d_in[5];
  const float* gw   = (const float*)d_in[6];
  const float* Wo   = (const float*)d_in[7];
  float* out = (float*)d_out;

  char* ws = (char*)d_ws;
  size_t off = 0;
  auto alloc = [&](size_t bytes)->char*{
    char* p = ws + off; off += (bytes + 255) & ~(size_t)255; return p;
  };
  u16*   Wt1   = (u16*)  alloc((size_t)QKVN*HID*2);        // Wqkv^T bf16 [3072,2048]
  u16*   Wt2   = (u16*)  alloc((size_t)HID*HID*2);         // Wo^T   bf16 [2048,2048]
  u16*   qkv   = (u16*)  alloc((size_t)T_TOK*QKVN*2);      // post-act q|k|v bf16
  float* gtmp  = (float*)alloc((size_t)T_TOK*16*4);
  float* g     = (float*)alloc((size_t)T_TOK*512*4);
  float* decay = (float*)alloc((size_t)NC*NKV*CHUNK*HD*4); // cumsum gates b_t
  float* expB  = (float*)alloc((size_t)NC*NKV*HD*4);
  float* Kmat  = (float*)alloc((size_t)NC*NKV*HD*HD*4);
  float* Sbuf  = (float*)alloc((size_t)NC*NKV*HD*HD*4);
  float* Abuf  = Kmat;  // Kmat dead after state_scan; same byte size (33.5MB)
  u16*   obuf  = (u16*) alloc((size_t)T_TOK*NH*HD*2);

  transpose_f2b<<<dim3(QKVN/32, HID/32), 256, 0, stream>>>(Wqkv, Wt1, HID, QKVN);
  transpose_f2b<<<dim3(HID/32,  HID/32), 256, 0, stream>>>(Wo,   Wt2, HID, HID);
  gemm_tpl<float,u16><<<dim3(T_TOK/128, QKVN/128), 256, 0, stream>>>(hs, Wt1, bqkv, qkv, T_TOK, QKVN, HID, 1);
  gk1_kernel<<<dim3(T_TOK/4), 256, 0, stream>>>(hs, w0, gtmp);
  gk2_kernel<<<dim3(T_TOK*512/256), 256, 0, stream>>>(gtmp, w1, b1, g);
  chunk_stats_kernel<<<dim3(NC, NKV), 256, 0, stream>>>(qkv, g, decay, expB, Kmat);
  state_scan_kernel<<<dim3(256), 256, 0, stream>>>(Kmat, expB, Sbuf);
  attn_a_kernel<<<dim3(NC, NH), 256, 0, stream>>>(qkv, decay, Abuf);
  attn_o_kernel<<<dim3(NC, NH), 256, 0, stream>>>(qkv, decay, Sbuf, Abuf, gw, obuf);
  gemm_tpl<u16,float><<<dim3(T_TOK/128, HID/128), 256, 0, stream>>>(obuf, Wt2, nullptr, out, T_TOK, HID, HID, 0);
}

// Round 3
// 749.968 us; speedup vs baseline: 1.0344x; 1.0344x over previous
//
#include <hip/hip_runtime.h>
#include <hip/hip_bf16.h>
#include <cstdint>

typedef unsigned short u16;
typedef unsigned int u32;
typedef float f32x4 __attribute__((ext_vector_type(4)));
typedef short bf16x8 __attribute__((ext_vector_type(8)));

#define T_TOK 8192
#define HID 2048
#define NH 16
#define NKV 4
#define HD 128
#define QKVN 3072   // (16+2*4)*128
#define CHUNK 64
#define NC 128      // 8192/64

__device__ __forceinline__ float bf2f(u16 h){
  u32 u = ((u32)h) << 16;
  return __builtin_bit_cast(float, u);
}
__device__ __forceinline__ u16 f2bf(float f){
  u32 u = __builtin_bit_cast(u32, f);
  u32 r = (u + 0x7fffu + ((u >> 16) & 1u)) >> 16;
  return (u16)r;
}
__device__ __forceinline__ u32 pack2(float a, float b){
  return (u32)f2bf(a) | ((u32)f2bf(b) << 16);
}
// async global->LDS, 16B per lane. LDS dest must be wave-uniform base + lane*16.
__device__ __forceinline__ void gl2lds16(const u16* g, u16* l){
  __builtin_amdgcn_global_load_lds(
      (const __attribute__((address_space(1))) u32*)g,
      (__attribute__((address_space(3))) u32*)l, 16, 0, 0);
}

// f32 -> bf16 bulk convert (8 elems/thread)
__global__ __launch_bounds__(256) void cvt_f2b_kernel(
    const float* __restrict__ in, u16* __restrict__ out, int n8)
{
  int i = blockIdx.x*256 + threadIdx.x;
  if (i >= n8) return;
  const float4* p = (const float4*)(in + (size_t)i*8);
  float4 a = p[0], b = p[1];
  uint4 pk;
  pk.x = pack2(a.x, a.y); pk.y = pack2(a.z, a.w);
  pk.z = pack2(b.x, b.y); pk.w = pack2(b.z, b.w);
  *(uint4*)(out + (size_t)i*8) = pk;
}

// ---------------------------------------------------------------------------
// m97-style GEMM: Y[M,N] = X[M,K](bf16) @ W[K,N] (W as bf16 Wt[N,K]) (+epilogue)
// 128x128 tile, BK=32, k-major unpadded LDS (128x32 bf16 = 8KB per tile),
// global_load_lds dwordx4 staging (LDS byte addr = j*4096 + tid*16).
// mode 0: plain. mode 1: qkv epilogue (bias f32; relu n<2560; *D^-0.5 n<2048)
// ---------------------------------------------------------------------------
template<typename YT>
__global__ __launch_bounds__(256) void gemm_m97(
    const u16* __restrict__ X, const u16* __restrict__ Wt,
    const float* __restrict__ bias, YT* __restrict__ Y,
    int M, int N, int K, int mode)
{
  __shared__ u16 As[128*32];
  __shared__ u16 Bs[128*32];
  const int tid = threadIdx.x;
  const int lane = tid & 63;
  const int wave = tid >> 6;
  const int wm = wave >> 1, wn = wave & 1;
  const int bm0 = blockIdx.x * 128, bn0 = blockIdx.y * 128;

  f32x4 acc[4][4];
  #pragma unroll
  for (int i=0;i<4;i++)
    #pragma unroll
    for (int j=0;j<4;j++) acc[i][j] = f32x4{0.f,0.f,0.f,0.f};

  const int row0 = tid >> 2, part8 = (tid & 3) * 8;   // chunk row / 8-elem part
  const int mrow = lane & 15, q8 = (lane >> 4) << 3;
  const u16* xb = X  + (size_t)bm0 * K;
  const u16* wb = Wt + (size_t)bn0 * K;

  for (int k0 = 0; k0 < K; k0 += 32) {
    #pragma unroll
    for (int j=0;j<2;j++){
      int rr = j*64 + row0;
      gl2lds16(xb + (size_t)rr*K + k0 + part8, As + rr*32 + part8);
      gl2lds16(wb + (size_t)rr*K + k0 + part8, Bs + rr*32 + part8);
    }
    __syncthreads();
    bf16x8 af[4], bfr[4];
    #pragma unroll
    for (int i=0;i<4;i++){
      af[i]  = *(const bf16x8*)(As + (wm*64 + i*16 + mrow)*32 + q8);
      bfr[i] = *(const bf16x8*)(Bs + (wn*64 + i*16 + mrow)*32 + q8);
    }
    #pragma unroll
    for (int i=0;i<4;i++)
      #pragma unroll
      for (int j=0;j<4;j++)
        acc[i][j] = __builtin_amdgcn_mfma_f32_16x16x32_bf16(af[i], bfr[j], acc[i][j], 0, 0, 0);
    __syncthreads();
  }
  // epilogue: C/D layout col=lane&15, row=(lane>>4)*4+reg (m89-verified)
  #pragma unroll
  for (int i=0;i<4;i++){
    int row = bm0 + wm*64 + i*16 + (lane>>4)*4;
    #pragma unroll
    for (int j=0;j<4;j++){
      int col = bn0 + wn*64 + j*16 + (lane&15);
      float bv = 0.f;
      if (mode == 1) bv = bias[col];
      #pragma unroll
      for (int rr2=0;rr2<4;rr2++){
        float v = acc[i][j][rr2] + bv;
        if (mode == 1 && col < 2560){
          v = fmaxf(v, 0.f);
          if (col < 2048) v *= 0.08838834764831845f;  // D^-0.5
        }
        if (sizeof(YT) == 2) Y[(size_t)(row+rr2)*N + col] = (YT)f2bf(v);
        else                 Y[(size_t)(row+rr2)*N + col] = (YT)v;
      }
    }
  }
}

// in[R,C] (f32) -> out[C,R] (bf16), 32x32 LDS tiles
__global__ __launch_bounds__(256) void transpose_f2b(
    const float* __restrict__ in, u16* __restrict__ out, int R, int C)
{
  __shared__ float tile[32][33];
  int c0 = blockIdx.x*32, r0 = blockIdx.y*32;
  int tx = threadIdx.x & 31, ty = threadIdx.x >> 5;
  #pragma unroll
  for (int p=0;p<4;p++) tile[ty + p*8][tx] = in[(size_t)(r0 + ty + p*8)*C + c0 + tx];
  __syncthreads();
  #pragma unroll
  for (int p=0;p<4;p++) out[(size_t)(c0 + ty + p*8)*R + r0 + tx] = f2bf(tile[tx][ty + p*8]);
}

// gate low-rank stage 1: tmp[T,16] = hs[T,2048] @ w0[2048,16]; one wave per row
__global__ __launch_bounds__(256) void gk1_kernel(
    const u16* __restrict__ hsb, const float* __restrict__ w0, float* __restrict__ tmp)
{
  int row = blockIdx.x*4 + (threadIdx.x >> 6);
  int lane = threadIdx.x & 63;
  float acc[16];
  #pragma unroll
  for (int n=0;n<16;n++) acc[n]=0.f;
  for (int k = lane; k < HID; k += 64){
    float h = bf2f(hsb[(size_t)row*HID + k]);
    const float* wr = w0 + (size_t)k*16;
    #pragma unroll
    for (int q=0;q<4;q++){
      float4 wv = *(const float4*)(wr + q*4);
      acc[q*4+0] += h*wv.x; acc[q*4+1] += h*wv.y;
      acc[q*4+2] += h*wv.z; acc[q*4+3] += h*wv.w;
    }
  }
  #pragma unroll
  for (int n=0;n<16;n++){
    #pragma unroll
    for (int off=32; off>0; off>>=1)
      acc[n] += __shfl_down(acc[n], off);
  }
  if (lane == 0){
    #pragma unroll
    for (int n=0;n<16;n++) tmp[(size_t)row*16 + n] = acc[n];
  }
}

// gate stage 2: g[T,512] = logsigmoid(tmp @ w1 + b1) / 16
__global__ __launch_bounds__(256) void gk2_kernel(
    const float* __restrict__ tmp, const float* __restrict__ w1,
    const float* __restrict__ b1, float* __restrict__ g)
{
  int id = blockIdx.x*256 + threadIdx.x;
  int rrow = id >> 9, n = id & 511;
  float a = b1[n];
  #pragma unroll
  for (int k=0;k<16;k++)
    a += tmp[(size_t)rrow*16 + k] * w1[k*512 + n];
  float ls = fminf(a, 0.f) - log1pf(__expf(-fabsf(a)));
  g[id] = ls * 0.0625f;
}

// Per (chunk c, kv-head h): cumsum gates b_t[i] (store decay), expB=e^{b_63},
// Kmat[i][j] = sum_t e^{B[i]-b_t[i]} k_t[i] v_t[j]
__global__ __launch_bounds__(256) void chunk_stats_kernel(
    const u16* __restrict__ qkv, const float* __restrict__ g,
    float* __restrict__ decay, float* __restrict__ expB, float* __restrict__ Kmat)
{
  __shared__ float bL[CHUNK*HD];   // gates -> cumsum -> kd (in place)
  __shared__ float vL[CHUNK*HD];
  const int c = blockIdx.x, h = blockIdx.y;
  const int tid = threadIdx.x;
  for (int off = tid; off < CHUNK*HD; off += 256){
    int t = off >> 7, i = off & 127;
    bL[off] = g[(size_t)(c*CHUNK + t)*512 + h*HD + i];
  }
  __syncthreads();
  if (tid < HD){
    float run = 0.f;
    for (int t=0;t<CHUNK;t++){ run += bL[t*HD + tid]; bL[t*HD + tid] = run; }
    expB[((size_t)c*NKV + h)*HD + tid] = __expf(run);
  }
  __syncthreads();
  const int myi = tid & 127;
  float Bfin = bL[63*HD + myi];
  __syncthreads();   // all Bfin reads before in-place kd overwrite
  for (int off = tid; off < CHUNK*HD; off += 256){
    int t = off >> 7, i = off & 127;   // i == myi for all iterations
    float b = bL[off];
    decay[(((size_t)c*NKV + h)*CHUNK + t)*HD + i] = b;
    float kv = bf2f(qkv[(size_t)(c*CHUNK + t)*QKVN + 2048 + h*HD + i]);
    bL[off] = __expf(Bfin - b) * kv;
    vL[off] = bf2f(qkv[(size_t)(c*CHUNK + t)*QKVN + 2560 + h*HD + i]);
  }
  __syncthreads();
  const int ii = tid >> 1, jh = (tid & 1) * 64;
  float acc[64];
  #pragma unroll
  for (int z=0;z<64;z++) acc[z]=0.f;
  for (int t=0;t<CHUNK;t++){
    float kd = bL[t*HD + ii];
    const float4* vp = (const float4*)(vL + t*HD + jh);
    #pragma unroll
    for (int jj=0;jj<16;jj++){
      float4 vv = vp[jj];
      acc[jj*4+0] += kd*vv.x; acc[jj*4+1] += kd*vv.y;
      acc[jj*4+2] += kd*vv.z; acc[jj*4+3] += kd*vv.w;
    }
  }
  float* Kp = Kmat + (((size_t)c*NKV + h)*HD + ii)*HD + jh;
  #pragma unroll
  for (int jj=0;jj<16;jj++)
    *(float4*)(Kp + jj*4) = make_float4(acc[jj*4+0],acc[jj*4+1],acc[jj*4+2],acc[jj*4+3]);
}

// Sequential over 128 chunks; each thread owns one (h,i,j) scalar recurrence.
__global__ __launch_bounds__(256) void state_scan_kernel(
    const float* __restrict__ Kmat, const float* __restrict__ expB, float* __restrict__ Sbuf)
{
  int wid = blockIdx.x;                 // 256 blocks
  int h = wid >> 6, i2 = wid & 63;
  int i = i2*2 + (threadIdx.x >> 7);
  int j = threadIdx.x & 127;
  size_t base = ((size_t)h*HD + i)*HD + j;
  float S = 0.f;
  for (int c=0;c<NC;c++){
    size_t off = (size_t)c*(NKV*HD*HD) + base;
    Sbuf[off] = S;
    S = expB[((size_t)c*NKV + h)*HD + i] * S + Kmat[off];
  }
}

// Per (chunk, q-head): A[t][s] = (t>=s) ? sum_i qe[t][i]*kd[s][i] : 0
__global__ __launch_bounds__(256) void attn_a_kernel(
    const u16* __restrict__ qkv, const float* __restrict__ decay, float* __restrict__ Abuf)
{
  __shared__ float qeT[HD*65];   // [i][t]
  __shared__ u16   kdT[HD*66];   // [i][t] bf16
  const int c = blockIdx.x, qh = blockIdx.y, h = qh >> 2;
  const int tid = threadIdx.x;
  for (int off = tid; off < CHUNK*HD; off += 256){
    int t = off >> 7, i = off & 127;
    size_t tok = (size_t)c*CHUNK + t;
    float b = decay[(((size_t)c*NKV + h)*CHUNK + t)*HD + i];
    float q = bf2f(qkv[tok*QKVN + qh*HD + i]);          // relu+scale done in GEMM
    float k = bf2f(qkv[tok*QKVN + 2048 + h*HD + i]);    // relu done in GEMM
    qeT[i*65 + t] = q * __expf(b);
    kdT[i*66 + t] = f2bf(k * __expf(-b));
  }
  __syncthreads();
  const int tb = (tid >> 4)*4, sb = (tid & 15)*4;
  float a[4][4];
  #pragma unroll
  for (int x=0;x<4;x++)
    #pragma unroll
    for (int y=0;y<4;y++) a[x][y]=0.f;
  for (int i=0;i<HD;i++){
    float qv[4], kv[4];
    #pragma unroll
    for (int e=0;e<4;e++){ qv[e] = qeT[i*65 + tb + e]; kv[e] = bf2f(kdT[i*66 + sb + e]); }
    #pragma unroll
    for (int x=0;x<4;x++)
      #pragma unroll
      for (int y=0;y<4;y++) a[x][y] += qv[x]*kv[y];
  }
  float* Ab = Abuf + ((size_t)c*NH + qh)*4096;
  #pragma unroll
  for (int x=0;x<4;x++)
    #pragma unroll
    for (int y=0;y<4;y++){
      int t = tb + x, s = sb + y;
      Ab[t*64 + s] = (t >= s) ? a[x][y] : 0.f;
    }
}

// Per (chunk, q-head): o = qe @ S_start + A @ V, then per-row RMSNorm -> obuf (bf16)
__global__ __launch_bounds__(256) void attn_o_kernel(
    const u16* __restrict__ qkv, const float* __restrict__ decay,
    const float* __restrict__ Sbuf, const float* __restrict__ Abuf,
    const float* __restrict__ gw, u16* __restrict__ obuf)
{
  __shared__ float smem[128*65 + 32*128];  // qeT + S-stage; reused as oL + rstd
  float* qeT = smem;
  float* sSt = smem + 128*65;
  const int c = blockIdx.x, qh = blockIdx.y, h = qh >> 2;
  const int tid = threadIdx.x;
  for (int off = tid; off < CHUNK*HD; off += 256){
    int t = off >> 7, i = off & 127;
    size_t tok = (size_t)c*CHUNK + t;
    float b = decay[(((size_t)c*NKV + h)*CHUNK + t)*HD + i];
    float q = bf2f(qkv[tok*QKVN + qh*HD + i]);
    qeT[i*65 + t] = q * __expf(b);
  }
  __syncthreads();
  const int tb = (tid >> 4)*4, jb = (tid & 15)*8;
  float o[4][8];
  #pragma unroll
  for (int x=0;x<4;x++)
    #pragma unroll
    for (int y=0;y<8;y++) o[x][y]=0.f;
  const float* Srow = Sbuf + ((size_t)c*NKV + h)*(HD*HD);
  for (int ic=0; ic<HD; ic+=32){
    #pragma unroll
    for (int p=0;p<4;p++){
      int fi = tid + p*256;
      ((float4*)sSt)[fi] = ((const float4*)(Srow + (size_t)ic*HD))[fi];
    }
    __syncthreads();
    for (int iiq=0; iiq<32; iiq++){
      int i = ic + iiq;
      float qv[4];
      #pragma unroll
      for (int e=0;e<4;e++) qv[e] = qeT[i*65 + tb + e];
      float4 s0 = *(const float4*)(sSt + iiq*HD + jb);
      float4 s1 = *(const float4*)(sSt + iiq*HD + jb + 4);
      float sv[8] = {s0.x,s0.y,s0.z,s0.w,s1.x,s1.y,s1.z,s1.w};
      #pragma unroll
      for (int x=0;x<4;x++)
        #pragma unroll
        for (int y=0;y<8;y++) o[x][y] += qv[x]*sv[y];
    }
    __syncthreads();
  }
  const float* Ab = Abuf + ((size_t)c*NH + qh)*4096;
  for (int s=0; s<CHUNK; s++){
    float av[4];
    #pragma unroll
    for (int e=0;e<4;e++) av[e] = Ab[(tb+e)*64 + s];
    uint4 vv = *(const uint4*)(qkv + (size_t)(c*CHUNK + s)*QKVN + 2560 + h*HD + jb);
    u32 vp[4] = {vv.x, vv.y, vv.z, vv.w};
    float vf[8];
    #pragma unroll
    for (int e=0;e<4;e++){ vf[2*e] = bf2f((u16)(vp[e]&0xffffu)); vf[2*e+1] = bf2f((u16)(vp[e]>>16)); }
    #pragma unroll
    for (int x=0;x<4;x++)
      #pragma unroll
      for (int y=0;y<8;y++) o[x][y] += av[x]*vf[y];
  }
  __syncthreads();
  float* oL = smem;               // [64][129]
  float* rst = smem + 64*129;
  #pragma unroll
  for (int x=0;x<4;x++)
    #pragma unroll
    for (int y=0;y<8;y++) oL[(tb+x)*129 + jb + y] = o[x][y];
  __syncthreads();
  if (tid < 64){
    float ss = 0.f;
    for (int j=0;j<HD;j++){ float x = oL[tid*129 + j]; ss += x*x; }
    rst[tid] = rsqrtf(ss * (1.f/128.f) + 1e-6f);
  }
  __syncthreads();
  for (int off = tid; off < CHUNK*HD; off += 256){
    int t = off >> 7, i = off & 127;
    float val = oL[t*129 + i] * rst[t] * gw[i];
    obuf[(size_t)(c*CHUNK + t)*(NH*HD) + qh*HD + i] = f2bf(val);
  }
}

extern "C" void kernel_launch(void* const* d_in, const int* in_sizes, int n_in,
                              void* d_out, int out_size, void* d_ws, size_t ws_size,
                              hipStream_t stream)
{
  const float* hs   = (const float*)d_in[0];
  const float* Wqkv = (const float*)d_in[1];
  const float* bqkv = (const float*)d_in[2];
  const float* w0   = (const float*)d_in[3];
  const float* w1   = (const float*)d_in[4];
  const float* b1   = (const float*)d_in[5];
  const float* gw   = (const float*)d_in[6];
  const float* Wo   = (const float*)d_in[7];
  float* out = (float*)d_out;

  char* ws = (char*)d_ws;
  size_t off = 0;
  auto alloc = [&](size_t bytes)->char*{
    char* p = ws + off; off += (bytes + 255) & ~(size_t)255; return p;
  };
  u16*   hsb   = (u16*)  alloc((size_t)T_TOK*HID*2);       // hs as bf16
  u16*   Wt1   = (u16*)  alloc((size_t)QKVN*HID*2);        // Wqkv^T bf16 [3072,2048]
  u16*   Wt2   = (u16*)  alloc((size_t)HID*HID*2);         // Wo^T   bf16 [2048,2048]
  u16*   qkv   = (u16*)  alloc((size_t)T_TOK*QKVN*2);      // post-act q|k|v bf16
  float* gtmp  = (float*)alloc((size_t)T_TOK*16*4);
  float* g     = (float*)alloc((size_t)T_TOK*512*4);
  float* decay = (float*)alloc((size_t)NC*NKV*CHUNK*HD*4); // cumsum gates b_t
  float* expB  = (float*)alloc((size_t)NC*NKV*HD*4);
  float* Kmat  = (float*)alloc((size_t)NC*NKV*HD*HD*4);
  float* Sbuf  = (float*)alloc((size_t)NC*NKV*HD*HD*4);
  float* Abuf  = Kmat;  // Kmat dead after state_scan; same byte size (33.5MB)
  u16*   obuf  = (u16*) alloc((size_t)T_TOK*NH*HD*2);

  cvt_f2b_kernel<<<dim3(T_TOK*HID/8/256), 256, 0, stream>>>(hs, hsb, T_TOK*HID/8);
  transpose_f2b<<<dim3(QKVN/32, HID/32), 256, 0, stream>>>(Wqkv, Wt1, HID, QKVN);
  transpose_f2b<<<dim3(HID/32,  HID/32), 256, 0, stream>>>(Wo,   Wt2, HID, HID);
  gemm_m97<u16><<<dim3(T_TOK/128, QKVN/128), 256, 0, stream>>>(hsb, Wt1, bqkv, qkv, T_TOK, QKVN, HID, 1);
  gk1_kernel<<<dim3(T_TOK/4), 256, 0, stream>>>(hsb, w0, gtmp);
  gk2_kernel<<<dim3(T_TOK*512/256), 256, 0, stream>>>(gtmp, w1, b1, g);
  chunk_stats_kernel<<<dim3(NC, NKV), 256, 0, stream>>>(qkv, g, decay, expB, Kmat);
  state_scan_kernel<<<dim3(256), 256, 0, stream>>>(Kmat, expB, Sbuf);
  attn_a_kernel<<<dim3(NC, NH), 256, 0, stream>>>(qkv, decay, Abuf);
  attn_o_kernel<<<dim3(NC, NH), 256, 0, stream>>>(qkv, decay, Sbuf, Abuf, gw, obuf);
  gemm_m97<float><<<dim3(T_TOK/128, HID/128), 256, 0, stream>>>(obuf, Wt2, nullptr, out, T_TOK, HID, HID, 0);
}

// Round 5
// 603.375 us; speedup vs baseline: 1.2857x; 1.2430x over previous
//
#include <hip/hip_runtime.h>
#include <hip/hip_bf16.h>
#include <cstdint>

typedef unsigned short u16;
typedef unsigned int u32;
typedef float f32x4 __attribute__((ext_vector_type(4)));
typedef short bf16x8 __attribute__((ext_vector_type(8)));

#define T_TOK 8192
#define HID 2048
#define NH 16
#define NKV 4
#define HD 128
#define QKVN 3072   // (16+2*4)*128
#define CHUNK 64
#define NC 128      // 8192/64

__device__ __forceinline__ float bf2f(u16 h){
  u32 u = ((u32)h) << 16;
  return __builtin_bit_cast(float, u);
}
__device__ __forceinline__ u16 f2bf(float f){
  u32 u = __builtin_bit_cast(u32, f);
  u32 r = (u + 0x7fffu + ((u >> 16) & 1u)) >> 16;
  return (u16)r;
}
__device__ __forceinline__ u32 pack2(float a, float b){
  return (u32)f2bf(a) | ((u32)f2bf(b) << 16);
}
// async global->LDS, 16B per lane. LDS dest must be wave-uniform base + lane*16.
__device__ __forceinline__ void gl2lds16(const u16* g, u16* l){
  __builtin_amdgcn_global_load_lds(
      (const __attribute__((address_space(1))) u32*)g,
      (__attribute__((address_space(3))) u32*)l, 16, 0, 0);
}

// f32 -> bf16 bulk convert (8 elems/thread)
__global__ __launch_bounds__(256) void cvt_f2b_kernel(
    const float* __restrict__ in, u16* __restrict__ out, int n8)
{
  int i = blockIdx.x*256 + threadIdx.x;
  if (i >= n8) return;
  const float4* p = (const float4*)(in + (size_t)i*8);
  float4 a = p[0], b = p[1];
  uint4 pk;
  pk.x = pack2(a.x, a.y); pk.y = pack2(a.z, a.w);
  pk.z = pack2(b.x, b.y); pk.w = pack2(b.z, b.w);
  *(uint4*)(out + (size_t)i*8) = pk;
}

// ---------------------------------------------------------------------------
// m97-style GEMM. mode 0: plain (Y f32). mode 1: qkv epilogue -> bf16:
//   q cols (<2048):      relu(v+bias)*D^-0.5 * ebuf[c,h,t,i]   (qe)
//   k cols (2048..2560): relu(v+bias)      * rbuf[c,h,t,i]     (kd)
//   v cols (>=2560):     v+bias
// ---------------------------------------------------------------------------
template<typename YT>
__global__ __launch_bounds__(256) void gemm_m97(
    const u16* __restrict__ X, const u16* __restrict__ Wt,
    const float* __restrict__ bias, const float* __restrict__ ebuf,
    const float* __restrict__ rbuf, YT* __restrict__ Y,
    int M, int N, int K, int mode)
{
  __shared__ u16 As[128*32];
  __shared__ u16 Bs[128*32];
  const int tid = threadIdx.x;
  const int lane = tid & 63;
  const int wave = tid >> 6;
  const int wm = wave >> 1, wn = wave & 1;
  const int bm0 = blockIdx.x * 128, bn0 = blockIdx.y * 128;

  f32x4 acc[4][4];
  #pragma unroll
  for (int i=0;i<4;i++)
    #pragma unroll
    for (int j=0;j<4;j++) acc[i][j] = f32x4{0.f,0.f,0.f,0.f};

  const int row0 = tid >> 2, part8 = (tid & 3) * 8;
  const int mrow = lane & 15, q8 = (lane >> 4) << 3;
  const u16* xb = X  + (size_t)bm0 * K;
  const u16* wb = Wt + (size_t)bn0 * K;

  for (int k0 = 0; k0 < K; k0 += 32) {
    #pragma unroll
    for (int j=0;j<2;j++){
      int rr = j*64 + row0;
      gl2lds16(xb + (size_t)rr*K + k0 + part8, As + rr*32 + part8);
      gl2lds16(wb + (size_t)rr*K + k0 + part8, Bs + rr*32 + part8);
    }
    __syncthreads();
    bf16x8 af[4], bfr[4];
    #pragma unroll
    for (int i=0;i<4;i++){
      af[i]  = *(const bf16x8*)(As + (wm*64 + i*16 + mrow)*32 + q8);
      bfr[i] = *(const bf16x8*)(Bs + (wn*64 + i*16 + mrow)*32 + q8);
    }
    #pragma unroll
    for (int i=0;i<4;i++)
      #pragma unroll
      for (int j=0;j<4;j++)
        acc[i][j] = __builtin_amdgcn_mfma_f32_16x16x32_bf16(af[i], bfr[j], acc[i][j], 0, 0, 0);
    __syncthreads();
  }
  // epilogue: C/D layout col=lane&15, row=(lane>>4)*4+reg
  #pragma unroll
  for (int i=0;i<4;i++){
    int row = bm0 + wm*64 + i*16 + (lane>>4)*4;
    #pragma unroll
    for (int j=0;j<4;j++){
      int col = bn0 + wn*64 + j*16 + (lane&15);
      float bv = 0.f;
      if (mode == 1) bv = bias[col];
      #pragma unroll
      for (int rr2=0;rr2<4;rr2++){
        float v = acc[i][j][rr2] + bv;
        if (mode == 1){
          int token = row + rr2;
          int cc = token >> 6, tt = token & 63, ii = col & 127;
          if (col < 2048){
            v = fmaxf(v, 0.f) * 0.08838834764831845f;
            v *= ebuf[(((size_t)cc*4 + (col>>9))*64 + tt)*128 + ii];
          } else if (col < 2560){
            v = fmaxf(v, 0.f);
            v *= rbuf[(((size_t)cc*4 + ((col-2048)>>7))*64 + tt)*128 + ii];
          }
        }
        if (sizeof(YT) == 2) Y[(size_t)(row+rr2)*N + col] = (YT)f2bf(v);
        else                 Y[(size_t)(row+rr2)*N + col] = (YT)v;
      }
    }
  }
}

// in[R,C] (f32) -> out[C,R] (bf16), 32x32 LDS tiles
__global__ __launch_bounds__(256) void transpose_f2b(
    const float* __restrict__ in, u16* __restrict__ out, int R, int C)
{
  __shared__ float tile[32][33];
  int c0 = blockIdx.x*32, r0 = blockIdx.y*32;
  int tx = threadIdx.x & 31, ty = threadIdx.x >> 5;
  #pragma unroll
  for (int p=0;p<4;p++) tile[ty + p*8][tx] = in[(size_t)(r0 + ty + p*8)*C + c0 + tx];
  __syncthreads();
  #pragma unroll
  for (int p=0;p<4;p++) out[(size_t)(c0 + ty + p*8)*R + r0 + tx] = f2bf(tile[tx][ty + p*8]);
}

// gate low-rank stage 1: tmp[T,16] = hs[T,2048] @ w0[2048,16]; one wave per row
__global__ __launch_bounds__(256) void gk1_kernel(
    const u16* __restrict__ hsb, const float* __restrict__ w0, float* __restrict__ tmp)
{
  int row = blockIdx.x*4 + (threadIdx.x >> 6);
  int lane = threadIdx.x & 63;
  float acc[16];
  #pragma unroll
  for (int n=0;n<16;n++) acc[n]=0.f;
  for (int k = lane; k < HID; k += 64){
    float h = bf2f(hsb[(size_t)row*HID + k]);
    const float* wr = w0 + (size_t)k*16;
    #pragma unroll
    for (int q=0;q<4;q++){
      float4 wv = *(const float4*)(wr + q*4);
      acc[q*4+0] += h*wv.x; acc[q*4+1] += h*wv.y;
      acc[q*4+2] += h*wv.z; acc[q*4+3] += h*wv.w;
    }
  }
  #pragma unroll
  for (int n=0;n<16;n++){
    #pragma unroll
    for (int off=32; off>0; off>>=1)
      acc[n] += __shfl_down(acc[n], off);
  }
  if (lane == 0){
    #pragma unroll
    for (int n=0;n<16;n++) tmp[(size_t)row*16 + n] = acc[n];
  }
}

// gate stage 2: g[T,512] = logsigmoid(tmp @ w1 + b1) / 16
__global__ __launch_bounds__(256) void gk2_kernel(
    const float* __restrict__ tmp, const float* __restrict__ w1,
    const float* __restrict__ b1, float* __restrict__ g)
{
  int id = blockIdx.x*256 + threadIdx.x;
  int rrow = id >> 9, n = id & 511;
  float a = b1[n];
  #pragma unroll
  for (int k=0;k<16;k++)
    a += tmp[(size_t)rrow*16 + k] * w1[k*512 + n];
  float ls = fminf(a, 0.f) - log1pf(__expf(-fabsf(a)));
  g[id] = ls * 0.0625f;
}

// Per (c,h): cumsum gates -> ebuf=e^b, rbuf=e^-b (f32), expB=e^{b_63}
__global__ __launch_bounds__(256) void decay_kernel(
    const float* __restrict__ g, float* __restrict__ ebuf,
    float* __restrict__ rbuf, float* __restrict__ expB)
{
  __shared__ float bL[CHUNK*HD];
  const int c = blockIdx.x, h = blockIdx.y, tid = threadIdx.x;
  for (int off = tid; off < CHUNK*HD; off += 256){
    int t = off >> 7, i = off & 127;
    bL[off] = g[(size_t)(c*CHUNK + t)*512 + h*HD + i];
  }
  __syncthreads();
  if (tid < HD){
    float run = 0.f;
    for (int t=0;t<CHUNK;t++){ run += bL[t*HD + tid]; bL[t*HD + tid] = run; }
    expB[(size_t)(c*NKV + h)*HD + tid] = __expf(run);
  }
  __syncthreads();
  size_t base = (size_t)(c*NKV + h)*CHUNK*HD;
  for (int off = tid; off < CHUNK*HD; off += 256){
    float b = bL[off];
    ebuf[base + off] = __expf(b);
    rbuf[base + off] = __expf(-b);
  }
}

// Per (c,h): Kt[j][i] = expB[i] * sum_t v[t][j]*kd[t][i] (bf16),
//            Vt[j][s] = v[s][j] (bf16)
__global__ __launch_bounds__(256) void chunk_stats2_kernel(
    const u16* __restrict__ qkv, const float* __restrict__ expB,
    u16* __restrict__ Kt, u16* __restrict__ Vt)
{
  __shared__ u16 kL[CHUNK*HD];
  __shared__ u16 vL[CHUNK*HD];
  const int c = blockIdx.x, h = blockIdx.y, tid = threadIdx.x;
  #pragma unroll
  for (int it=0; it<4; it++){
    int u = it*256 + tid;              // 0..1023, one uint4 each of kL,vL
    int t = u >> 4, p = (u & 15)*8;
    size_t tok = (size_t)(c*CHUNK + t);
    *(uint4*)(kL + t*HD + p) = *(const uint4*)(qkv + tok*QKVN + 2048 + h*HD + p);
    *(uint4*)(vL + t*HD + p) = *(const uint4*)(qkv + tok*QKVN + 2560 + h*HD + p);
  }
  __syncthreads();
  // Vt emit
  {
    int j = tid >> 1, sh = (tid & 1)*32;
    u16* dst = Vt + ((size_t)(c*NKV + h)*HD + j)*CHUNK + sh;
    #pragma unroll
    for (int s2=0; s2<16; s2++){
      u32 a = (u32)vL[(sh + 2*s2)*HD + j] | ((u32)vL[(sh + 2*s2 + 1)*HD + j] << 16);
      *(u32*)(dst + 2*s2) = a;
    }
  }
  // Kt
  int jj = tid >> 1, ih = (tid & 1)*64;
  float acc[64];
  #pragma unroll
  for (int z=0;z<64;z++) acc[z]=0.f;
  for (int t=0;t<CHUNK;t++){
    float vj = bf2f(vL[t*HD + jj]);
    const u32* kp = (const u32*)(kL + t*HD + ih);
    #pragma unroll
    for (int z2=0; z2<32; z2++){
      u32 kw = kp[z2];
      acc[2*z2]   += vj * bf2f((u16)(kw & 0xffffu));
      acc[2*z2+1] += vj * bf2f((u16)(kw >> 16));
    }
  }
  u16* kout = Kt + ((size_t)(c*NKV + h)*HD + jj)*HD + ih;
  const float* eB = expB + (size_t)(c*NKV + h)*HD + ih;
  #pragma unroll
  for (int z2=0; z2<32; z2++)
    *(u32*)(kout + 2*z2) = pack2(acc[2*z2]*eB[2*z2], acc[2*z2+1]*eB[2*z2+1]);
}

// Sequential scan over chunks in transposed layout; St[c][h][j][i] bf16.
__global__ __launch_bounds__(256) void state_scan2_kernel(
    const u16* __restrict__ Kt, const float* __restrict__ expB, u16* __restrict__ St)
{
  int wid = blockIdx.x;                 // 256 blocks
  int h = wid >> 6;
  int j = (wid & 63)*2 + (threadIdx.x >> 7);
  int i = threadIdx.x & 127;
  size_t base = ((size_t)h*HD + j)*HD + i;
  float S = 0.f;
  for (int cc=0; cc<NC; cc++){
    size_t off = (size_t)cc*(NKV*HD*HD) + base;
    St[off] = f2bf(S);
    S = expB[((size_t)cc*NKV + h)*HD + i] * S + bf2f(Kt[off]);
  }
}

// Fused intra-chunk attention per (c, qh):
//   A = tril(qe @ kd^T)  [64x64]  -> P (LDS, bf16)
//   o = P @ Vt + qe @ St [64x128], RMSNorm rows, -> obuf bf16
// Wave w owns rows [w*16, w*16+16). MFMA 16x16x32 bf16 throughout.
__global__ __launch_bounds__(256) void attn_fused_kernel(
    const u16* __restrict__ qkv, const u16* __restrict__ St,
    const u16* __restrict__ Vt, const float* __restrict__ gw,
    u16* __restrict__ obuf)
{
  __shared__ u16 qe[64*136];
  __shared__ u16 kb[64*136];   // kd; later St rows 64..127
  __shared__ u16 sb[64*136];   // St rows 0..63
  __shared__ u16 vb[128*72];   // Vt [j][s]
  __shared__ u16 pb[64*72];    // P  [t][s]
  const int c = blockIdx.x, qh = blockIdx.y, h = qh >> 2;
  const int tid = threadIdx.x, lane = tid & 63, w = tid >> 6;
  const int ml = lane & 15, quad = lane >> 4, q8 = quad * 8;

  // stage qe, kd (64 rows x 128 cols = 1024 uint4 each)
  #pragma unroll
  for (int it = 0; it < 4; it++){
    int u = it*256 + tid;              // 0..1023
    int t = u >> 4, p = (u & 15) * 8;
    size_t tok = (size_t)(c*CHUNK + t);
    *(uint4*)(qe + t*136 + p) = *(const uint4*)(qkv + tok*QKVN + qh*HD + p);
    *(uint4*)(kb + t*136 + p) = *(const uint4*)(qkv + tok*QKVN + 2048 + h*HD + p);
  }
  __syncthreads();

  // A phase
  bf16x8 aq[4];
  #pragma unroll
  for (int kk=0;kk<4;kk++)
    aq[kk] = *(const bf16x8*)(qe + (w*16 + ml)*136 + kk*32 + q8);
  #pragma unroll
  for (int n=0;n<4;n++){
    f32x4 pa = {0.f,0.f,0.f,0.f};
    #pragma unroll
    for (int kk=0;kk<4;kk++){
      bf16x8 bk = *(const bf16x8*)(kb + (n*16 + ml)*136 + kk*32 + q8);
      pa = __builtin_amdgcn_mfma_f32_16x16x32_bf16(aq[kk], bk, pa, 0, 0, 0);
    }
    #pragma unroll
    for (int r=0;r<4;r++){
      int ti = quad*4 + r;
      float v = (w*16 + ti >= n*16 + ml) ? pa[r] : 0.f;
      pb[(w*16 + ti)*72 + n*16 + ml] = f2bf(v);
    }
  }
  // stage Vt (128x64 = 1024 uint4) + St rows 0..63 (64x128 = 1024 uint4)
  #pragma unroll
  for (int it = 0; it < 4; it++){
    int u = it*256 + tid;              // 0..1023
    int j = u >> 3, p = (u & 7) * 8;
    *(uint4*)(vb + j*72 + p) =
        *(const uint4*)(Vt + ((size_t)(c*NKV + h)*HD + j)*CHUNK + p);
    int t2 = u >> 4, p2 = (u & 15) * 8;
    *(uint4*)(sb + t2*136 + p2) =
        *(const uint4*)(St + ((size_t)(c*NKV + h)*HD + t2)*HD + p2);
  }
  __syncthreads();   // A-phase done everywhere; pb/vb/sb ready; kb now dead

  f32x4 o[8];
  #pragma unroll
  for (int n=0;n<8;n++) o[n] = f32x4{0.f,0.f,0.f,0.f};
  // o += P @ Vt (K=64)
  bf16x8 ap[2];
  #pragma unroll
  for (int ks=0;ks<2;ks++)
    ap[ks] = *(const bf16x8*)(pb + (w*16 + ml)*72 + ks*32 + q8);
  #pragma unroll
  for (int n=0;n<8;n++)
    #pragma unroll
    for (int ks=0;ks<2;ks++){
      bf16x8 bv = *(const bf16x8*)(vb + (n*16 + ml)*72 + ks*32 + q8);
      o[n] = __builtin_amdgcn_mfma_f32_16x16x32_bf16(ap[ks], bv, o[n], 0, 0, 0);
    }
  // o += qe @ St (j tiles 0..3 from sb)
  #pragma unroll
  for (int n=0;n<4;n++)
    #pragma unroll
    for (int kk=0;kk<4;kk++){
      bf16x8 bs = *(const bf16x8*)(sb + (n*16 + ml)*136 + kk*32 + q8);
      o[n] = __builtin_amdgcn_mfma_f32_16x16x32_bf16(aq[kk], bs, o[n], 0, 0, 0);
    }
  // stage St rows 64..127 into kb (1024 uint4)
  #pragma unroll
  for (int it = 0; it < 4; it++){
    int u = it*256 + tid;
    int t2 = u >> 4, p2 = (u & 15) * 8;
    *(uint4*)(kb + t2*136 + p2) =
        *(const uint4*)(St + ((size_t)(c*NKV + h)*HD + 64 + t2)*HD + p2);
  }
  __syncthreads();
  #pragma unroll
  for (int n=0;n<4;n++)
    #pragma unroll
    for (int kk=0;kk<4;kk++){
      bf16x8 bs = *(const bf16x8*)(kb + (n*16 + ml)*136 + kk*32 + q8);
      o[4+n] = __builtin_amdgcn_mfma_f32_16x16x32_bf16(aq[kk], bs, o[4+n], 0, 0, 0);
    }

  // RMSNorm per row (rows live in (quad, reg); reduce across 16 lanes of quad)
  float rstd[4];
  #pragma unroll
  for (int r=0;r<4;r++){
    float s = 0.f;
    #pragma unroll
    for (int n=0;n<8;n++) s += o[n][r]*o[n][r];
    #pragma unroll
    for (int off=1; off<16; off<<=1) s += __shfl_xor(s, off);
    rstd[r] = rsqrtf(s*(1.f/128.f) + 1e-6f);
  }
  #pragma unroll
  for (int n=0;n<8;n++){
    float gwv = gw[n*16 + ml];
    #pragma unroll
    for (int r=0;r<4;r++){
      int t = w*16 + quad*4 + r;
      float val = o[n][r] * rstd[r] * gwv;
      obuf[(size_t)(c*CHUNK + t)*(NH*HD) + qh*HD + n*16 + ml] = f2bf(val);
    }
  }
}

extern "C" void kernel_launch(void* const* d_in, const int* in_sizes, int n_in,
                              void* d_out, int out_size, void* d_ws, size_t ws_size,
                              hipStream_t stream)
{
  const float* hs   = (const float*)d_in[0];
  const float* Wqkv = (const float*)d_in[1];
  const float* bqkv = (const float*)d_in[2];
  const float* w0   = (const float*)d_in[3];
  const float* w1   = (const float*)d_in[4];
  const float* b1   = (const float*)d_in[5];
  const float* gw   = (const float*)d_in[6];
  const float* Wo   = (const float*)d_in[7];
  float* out = (float*)d_out;

  char* ws = (char*)d_ws;
  size_t off = 0;
  auto alloc = [&](size_t bytes)->char*{
    char* p = ws + off; off += (bytes + 255) & ~(size_t)255; return p;
  };
  u16*   hsb   = (u16*)  alloc((size_t)T_TOK*HID*2);        // hs bf16
  u16*   Wt1   = (u16*)  alloc((size_t)QKVN*HID*2);         // Wqkv^T bf16
  u16*   Wt2   = (u16*)  alloc((size_t)HID*HID*2);          // Wo^T bf16
  u16*   qkv   = (u16*)  alloc((size_t)T_TOK*QKVN*2);       // qe | kd | v  bf16
  float* gtmp  = (float*)alloc((size_t)T_TOK*16*4);
  float* g     = (float*)alloc((size_t)T_TOK*512*4);
  float* ebuf  = (float*)alloc((size_t)NC*NKV*CHUNK*HD*4);  // e^{b}
  float* rbuf  = (float*)alloc((size_t)NC*NKV*CHUNK*HD*4);  // e^{-b}
  float* expB  = (float*)alloc((size_t)NC*NKV*HD*4);        // e^{b_63}
  u16*   Kt    = (u16*)  alloc((size_t)NC*NKV*HD*HD*2);     // bf16 [j][i]
  u16*   St    = (u16*)  alloc((size_t)NC*NKV*HD*HD*2);     // bf16 [j][i]
  u16*   Vt    = (u16*)  alloc((size_t)NC*NKV*HD*CHUNK*2);  // bf16 [j][s]
  u16*   obuf  = (u16*)  alloc((size_t)T_TOK*NH*HD*2);

  cvt_f2b_kernel<<<dim3(T_TOK*HID/8/256), 256, 0, stream>>>(hs, hsb, T_TOK*HID/8);
  transpose_f2b<<<dim3(QKVN/32, HID/32), 256, 0, stream>>>(Wqkv, Wt1, HID, QKVN);
  transpose_f2b<<<dim3(HID/32,  HID/32), 256, 0, stream>>>(Wo,   Wt2, HID, HID);
  gk1_kernel<<<dim3(T_TOK/4), 256, 0, stream>>>(hsb, w0, gtmp);
  gk2_kernel<<<dim3(T_TOK*512/256), 256, 0, stream>>>(gtmp, w1, b1, g);
  decay_kernel<<<dim3(NC, NKV), 256, 0, stream>>>(g, ebuf, rbuf, expB);
  gemm_m97<u16><<<dim3(T_TOK/128, QKVN/128), 256, 0, stream>>>(
      hsb, Wt1, bqkv, ebuf, rbuf, qkv, T_TOK, QKVN, HID, 1);
  chunk_stats2_kernel<<<dim3(NC, NKV), 256, 0, stream>>>(qkv, expB, Kt, Vt);
  state_scan2_kernel<<<dim3(256), 256, 0, stream>>>(Kt, expB, St);
  attn_fused_kernel<<<dim3(NC, NH), 256, 0, stream>>>(qkv, St, Vt, gw, obuf);
  gemm_m97<float><<<dim3(T_TOK/128, HID/128), 256, 0, stream>>>(
      obuf, Wt2, nullptr, nullptr, nullptr, out, T_TOK, HID, HID, 0);
}